// Round 2
// baseline (1089.951 us; speedup 1.0000x reference)
//
#include <hip/hip_runtime.h>

#define N_NODES 100000
#define N_EDGES 1600000
#define HIDDEN 64
#define RPB 64                       // rows per bucket
#define NB ((N_NODES + RPB - 1) / RPB)   // 1563 buckets

// ---------------- Phase A1: histogram edges per bucket ----------------
__global__ void hist_kernel(const int* __restrict__ rows, int* __restrict__ cnt) {
    int i = blockIdx.x * blockDim.x + threadIdx.x;
    const int stride = gridDim.x * blockDim.x;
    for (; i < N_EDGES; i += stride) {
        atomicAdd(&cnt[rows[i] >> 6], 1);
    }
}

// ---------------- Phase A2: exclusive scan of 1563 counts (1 block) ----------------
__global__ void scan_kernel(const int* __restrict__ cnt, int* __restrict__ offs,
                            int* __restrict__ cursor) {
    __shared__ int buf[2][2048];
    const int t = threadIdx.x;  // 1024 threads
    buf[0][t]        = (t        < NB) ? cnt[t]        : 0;
    buf[0][t + 1024] = (t + 1024 < NB) ? cnt[t + 1024] : 0;
    __syncthreads();
    int src = 0;
    for (int off = 1; off < 2048; off <<= 1) {
        int i0 = t, i1 = t + 1024;
        buf[1 - src][i0] = buf[src][i0] + (i0 >= off ? buf[src][i0 - off] : 0);
        buf[1 - src][i1] = buf[src][i1] + (i1 >= off ? buf[src][i1 - off] : 0);
        __syncthreads();
        src ^= 1;
    }
    // buf[src] holds inclusive scan; emit exclusive offs[0..NB] and cursor copy
    for (int i = t; i <= NB; i += 1024) {
        int v = (i == 0) ? 0 : buf[src][i - 1];
        offs[i] = v;
        if (i < NB) cursor[i] = v;
    }
}

// ---------------- Phase A3: scatter edges into bucket-contiguous buffer ----------------
// packed = (row&63)<<17 | col   (col < 100000 < 2^17)
__global__ void reorder_kernel(const int* __restrict__ rows, const int* __restrict__ cols,
                               const float* __restrict__ vals, int* __restrict__ cursor,
                               int2* __restrict__ ebuf) {
    int i = blockIdx.x * blockDim.x + threadIdx.x;
    const int stride = gridDim.x * blockDim.x;
    for (; i < N_EDGES; i += stride) {
        const int r = rows[i];
        const int b = r >> 6;
        const int pos = atomicAdd(&cursor[b], 1);
        ebuf[pos] = make_int2(((r & 63) << 17) | cols[i], __float_as_int(vals[i]));
    }
}

// ---------------- Phase B: per-bucket gather + LDS accumulate + fused ReLU store ----------
__global__ void __launch_bounds__(256) bucket_accum_kernel(
        const float* __restrict__ x, const int2* __restrict__ ebuf,
        const int* __restrict__ offs, float* __restrict__ out) {
    __shared__ float acc[RPB * HIDDEN];  // 16 KB
    const int t = threadIdx.x;
    #pragma unroll
    for (int i = t; i < RPB * HIDDEN; i += 256) acc[i] = 0.0f;
    __syncthreads();

    const int b = blockIdx.x;
    const int start = offs[b], end = offs[b + 1];
    const int lane = t & 63;
    const int wave = t >> 6;  // 4 waves per block

    // 2 edges in flight per wave to hide the dependent meta->gather chain
    for (int e = start + wave; e < end; e += 8) {
        const int e2 = e + 4;
        const int2 m1 = ebuf[e];
        const bool has2 = (e2 < end);
        const int2 m2 = has2 ? ebuf[e2] : make_int2(0, 0);

        const int c1 = m1.x & 0x1FFFF;
        const float x1 = x[(size_t)c1 * HIDDEN + lane];
        float x2 = 0.0f;
        int rl2 = 0;
        float v2 = 0.0f;
        if (has2) {
            const int c2 = m2.x & 0x1FFFF;
            x2 = x[(size_t)c2 * HIDDEN + lane];
            rl2 = (m2.x >> 17) & 63;
            v2 = __int_as_float(m2.y);
        }
        const int rl1 = (m1.x >> 17) & 63;
        const float v1 = __int_as_float(m1.y);
        atomicAdd(&acc[rl1 * HIDDEN + lane], v1 * x1);
        if (has2) atomicAdd(&acc[rl2 * HIDDEN + lane], v2 * x2);
    }
    __syncthreads();

    // Write bucket tile with fused ReLU (coalesced).
    const int baseRow = b * RPB;
    for (int i = t; i < RPB * HIDDEN; i += 256) {
        const int row = baseRow + (i >> 6);
        if (row < N_NODES) out[(size_t)row * HIDDEN + (i & 63)] = fmaxf(acc[i], 0.0f);
    }
}

// ---------------- Fallback (round-1 path) if ws too small ----------------
__global__ void spmm_scatter_kernel(const float* __restrict__ x,
                                    const int* __restrict__ rows,
                                    const int* __restrict__ cols,
                                    const float* __restrict__ vals,
                                    float* __restrict__ f) {
    const int lane = threadIdx.x & 63;
    const int wave = (blockIdx.x * blockDim.x + threadIdx.x) >> 6;
    const int nWaves = (gridDim.x * blockDim.x) >> 6;
    for (int e = wave; e < N_EDGES; e += nWaves) {
        const int r = rows[e];
        const int c = cols[e];
        const float v = vals[e];
        atomicAdd(&f[r * HIDDEN + lane], v * x[c * HIDDEN + lane]);
    }
}
__global__ void relu_inplace_kernel(float4* __restrict__ f, int n4) {
    int i = blockIdx.x * blockDim.x + threadIdx.x;
    const int stride = gridDim.x * blockDim.x;
    for (; i < n4; i += stride) {
        float4 v = f[i];
        v.x = fmaxf(v.x, 0.0f); v.y = fmaxf(v.y, 0.0f);
        v.z = fmaxf(v.z, 0.0f); v.w = fmaxf(v.w, 0.0f);
        f[i] = v;
    }
}

extern "C" void kernel_launch(void* const* d_in, const int* in_sizes, int n_in,
                              void* d_out, int out_size, void* d_ws, size_t ws_size,
                              hipStream_t stream) {
    const float* x    = (const float*)d_in[1];
    const int*   rows = (const int*)d_in[2];
    const int*   cols = (const int*)d_in[3];
    const float* vals = (const float*)d_in[4];
    float* out = (float*)d_out;

    // ws layout: cnt[NB] | offs[NB+1] | cursor[NB] | ebuf[E] (int2, 16B-aligned)
    const size_t cnt_off    = 0;
    const size_t offs_off   = cnt_off + (size_t)NB * 4;
    const size_t cursor_off = offs_off + (size_t)(NB + 1) * 4;
    size_t ebuf_off = cursor_off + (size_t)NB * 4;
    ebuf_off = (ebuf_off + 15) & ~(size_t)15;
    const size_t ws_needed = ebuf_off + (size_t)N_EDGES * 8;

    if (ws_size >= ws_needed) {
        char* ws = (char*)d_ws;
        int*  cnt    = (int*)(ws + cnt_off);
        int*  offs   = (int*)(ws + offs_off);
        int*  cursor = (int*)(ws + cursor_off);
        int2* ebuf   = (int2*)(ws + ebuf_off);

        hipMemsetAsync(cnt, 0, (size_t)NB * 4, stream);
        hist_kernel<<<2048, 256, 0, stream>>>(rows, cnt);
        scan_kernel<<<1, 1024, 0, stream>>>(cnt, offs, cursor);
        reorder_kernel<<<2048, 256, 0, stream>>>(rows, cols, vals, cursor, ebuf);
        bucket_accum_kernel<<<NB, 256, 0, stream>>>(x, ebuf, offs, out);
    } else {
        // Fallback: global-atomic scatter (round-1 path)
        hipMemsetAsync(d_out, 0, (size_t)N_NODES * HIDDEN * sizeof(float), stream);
        spmm_scatter_kernel<<<2048, 256, 0, stream>>>(x, rows, cols, vals, out);
        relu_inplace_kernel<<<2048, 256, 0, stream>>>((float4*)d_out,
                                                      (N_NODES * HIDDEN) / 4);
    }
}

// Round 3
// 266.888 us; speedup vs baseline: 4.0839x; 4.0839x over previous
//
#include <hip/hip_runtime.h>

#define N_NODES 100000
#define N_EDGES 1600000
#define HIDDEN 64
#define CHUNK 1024
#define NCHUNK ((N_NODES + CHUNK - 1) / CHUNK)   // 98

// ---------------- A1: per-row histogram (100K counters, avg 16 hits each) ----------
__global__ void hist_kernel(const int* __restrict__ rows, int* __restrict__ cnt) {
    int i = blockIdx.x * blockDim.x + threadIdx.x;
    const int stride = gridDim.x * blockDim.x;
    for (; i < N_EDGES; i += stride) atomicAdd(&cnt[rows[i]], 1);
}

// ---------------- A2a: per-chunk inclusive scan; incl[i] stored at offs[i+1] --------
__global__ void __launch_bounds__(1024) scan1_kernel(const int* __restrict__ cnt,
                                                     int* __restrict__ offs,
                                                     int* __restrict__ partials) {
    __shared__ int s[2][CHUNK];
    const int t = threadIdx.x, b = blockIdx.x;
    const int i = b * CHUNK + t;
    s[0][t] = (i < N_NODES) ? cnt[i] : 0;
    __syncthreads();
    int src = 0;
    for (int off = 1; off < CHUNK; off <<= 1) {
        s[1 - src][t] = s[src][t] + (t >= off ? s[src][t - off] : 0);
        __syncthreads();
        src ^= 1;
    }
    const int incl = s[src][t];
    if (i < N_NODES) offs[i + 1] = incl;
    if (t == CHUNK - 1) partials[b] = incl;
}

// ---------------- A2b: exclusive scan of 98 chunk totals (trivial serial) ----------
__global__ void scan2_kernel(int* __restrict__ partials) {
    if (threadIdx.x == 0) {
        int run = 0;
        for (int i = 0; i < NCHUNK; ++i) {
            int v = partials[i];
            partials[i] = run;
            run += v;
        }
    }
}

// ---------------- A2c: finalize exclusive offs[] and cursor (cnt reused) -----------
__global__ void __launch_bounds__(1024) scan3_kernel(int* __restrict__ offs,
                                                     const int* __restrict__ partials,
                                                     int* __restrict__ cursor) {
    const int i = blockIdx.x * CHUNK + threadIdx.x;  // 0..100351
    if (i > N_NODES) return;
    int val;
    if (i == 0) val = 0;
    else        val = offs[i] + partials[(i - 1) / CHUNK];
    offs[i] = val;
    if (i < N_NODES) cursor[i] = val;
}

// ---------------- A3: reorder edges into row-sorted buffer -------------------------
__global__ void reorder_kernel(const int* __restrict__ rows, const int* __restrict__ cols,
                               const float* __restrict__ vals, int* __restrict__ cursor,
                               int2* __restrict__ ebuf) {
    int i = blockIdx.x * blockDim.x + threadIdx.x;
    const int stride = gridDim.x * blockDim.x;
    for (; i < N_EDGES; i += stride) {
        const int pos = atomicAdd(&cursor[rows[i]], 1);
        ebuf[pos] = make_int2(cols[i], __float_as_int(vals[i]));
    }
}

// ---------------- B: CSR SpMM, one wave per row, register accumulate, fused ReLU ----
__global__ void __launch_bounds__(256) spmm_csr_relu_kernel(
        const float* __restrict__ x, const int2* __restrict__ ebuf,
        const int* __restrict__ offs, float* __restrict__ out) {
    const int lane = threadIdx.x & 63;
    const int wave = threadIdx.x >> 6;          // 4 waves/block
    const int r = blockIdx.x * 4 + wave;        // 25000 blocks * 4 = 100000 rows
    if (r >= N_NODES) return;
    const int start = offs[r];
    const int n = offs[r + 1] - start;

    float acc = 0.0f;
    for (int base = 0; base < n; base += 64) {
        const int take = min(64, n - base);
        int2 m = make_int2(0, 0);
        if (base + lane < n) m = ebuf[start + base + lane];  // coalesced meta load
        int j = 0;
        for (; j + 3 < take; j += 4) {
            const int   c0 = __shfl(m.x, j);
            const int   c1 = __shfl(m.x, j + 1);
            const int   c2 = __shfl(m.x, j + 2);
            const int   c3 = __shfl(m.x, j + 3);
            const float v0 = __int_as_float(__shfl(m.y, j));
            const float v1 = __int_as_float(__shfl(m.y, j + 1));
            const float v2 = __int_as_float(__shfl(m.y, j + 2));
            const float v3 = __int_as_float(__shfl(m.y, j + 3));
            const float x0 = x[(size_t)c0 * HIDDEN + lane];
            const float x1 = x[(size_t)c1 * HIDDEN + lane];
            const float x2 = x[(size_t)c2 * HIDDEN + lane];
            const float x3 = x[(size_t)c3 * HIDDEN + lane];
            acc = fmaf(v0, x0, acc);
            acc = fmaf(v1, x1, acc);
            acc = fmaf(v2, x2, acc);
            acc = fmaf(v3, x3, acc);
        }
        for (; j < take; ++j) {
            const int   c = __shfl(m.x, j);
            const float v = __int_as_float(__shfl(m.y, j));
            acc = fmaf(v, x[(size_t)c * HIDDEN + lane], acc);
        }
    }
    out[(size_t)r * HIDDEN + lane] = fmaxf(acc, 0.0f);
}

// ---------------- Fallback (round-1 path) if ws too small --------------------------
__global__ void spmm_scatter_kernel(const float* __restrict__ x,
                                    const int* __restrict__ rows,
                                    const int* __restrict__ cols,
                                    const float* __restrict__ vals,
                                    float* __restrict__ f) {
    const int lane = threadIdx.x & 63;
    const int wave = (blockIdx.x * blockDim.x + threadIdx.x) >> 6;
    const int nWaves = (gridDim.x * blockDim.x) >> 6;
    for (int e = wave; e < N_EDGES; e += nWaves)
        atomicAdd(&f[rows[e] * HIDDEN + lane], vals[e] * x[cols[e] * HIDDEN + lane]);
}
__global__ void relu_inplace_kernel(float4* __restrict__ f, int n4) {
    int i = blockIdx.x * blockDim.x + threadIdx.x;
    const int stride = gridDim.x * blockDim.x;
    for (; i < n4; i += stride) {
        float4 v = f[i];
        v.x = fmaxf(v.x, 0.0f); v.y = fmaxf(v.y, 0.0f);
        v.z = fmaxf(v.z, 0.0f); v.w = fmaxf(v.w, 0.0f);
        f[i] = v;
    }
}

extern "C" void kernel_launch(void* const* d_in, const int* in_sizes, int n_in,
                              void* d_out, int out_size, void* d_ws, size_t ws_size,
                              hipStream_t stream) {
    const float* x    = (const float*)d_in[1];
    const int*   rows = (const int*)d_in[2];
    const int*   cols = (const int*)d_in[3];
    const float* vals = (const float*)d_in[4];
    float* out = (float*)d_out;

    // ws layout: cnt[N] (reused as cursor) | offs[N+1] | partials[NCHUNK] | ebuf[E]
    const size_t cnt_off      = 0;
    const size_t offs_off     = cnt_off + (size_t)N_NODES * 4;
    const size_t partials_off = offs_off + (size_t)(N_NODES + 1) * 4;
    size_t ebuf_off = partials_off + (size_t)NCHUNK * 4;
    ebuf_off = (ebuf_off + 15) & ~(size_t)15;
    const size_t ws_needed = ebuf_off + (size_t)N_EDGES * 8;

    if (ws_size >= ws_needed) {
        char* ws = (char*)d_ws;
        int*  cnt      = (int*)(ws + cnt_off);     // histogram, then cursor
        int*  offs     = (int*)(ws + offs_off);
        int*  partials = (int*)(ws + partials_off);
        int2* ebuf     = (int2*)(ws + ebuf_off);

        hipMemsetAsync(cnt, 0, (size_t)N_NODES * 4, stream);
        hist_kernel<<<2048, 256, 0, stream>>>(rows, cnt);
        scan1_kernel<<<NCHUNK, CHUNK, 0, stream>>>(cnt, offs, partials);
        scan2_kernel<<<1, 64, 0, stream>>>(partials);
        scan3_kernel<<<NCHUNK, CHUNK, 0, stream>>>(offs, partials, cnt);
        reorder_kernel<<<2048, 256, 0, stream>>>(rows, cols, vals, cnt, ebuf);
        spmm_csr_relu_kernel<<<N_NODES / 4, 256, 0, stream>>>(x, ebuf, offs, out);
    } else {
        hipMemsetAsync(d_out, 0, (size_t)N_NODES * HIDDEN * sizeof(float), stream);
        spmm_scatter_kernel<<<2048, 256, 0, stream>>>(x, rows, cols, vals, out);
        relu_inplace_kernel<<<2048, 256, 0, stream>>>((float4*)d_out,
                                                      (N_NODES * HIDDEN) / 4);
    }
}

// Round 4
// 213.370 us; speedup vs baseline: 5.1083x; 1.2508x over previous
//
#include <hip/hip_runtime.h>

#define N_NODES 100000
#define N_EDGES 1600000
#define HIDDEN 64
#define CHUNK 1024
#define NCHUNK ((N_NODES + CHUNK - 1) / CHUNK)   // 98 scan chunks
#define NCB NCHUNK                               // 98 coarse buckets (1024 rows each)
#define R1_BATCH 4096
#define R1_PER_T (R1_BATCH / 256)                // 16 edges per thread

// ---------------- A1: per-row histogram ----------------
__global__ void hist_kernel(const int* __restrict__ rows, int* __restrict__ cnt) {
    int i = blockIdx.x * blockDim.x + threadIdx.x;
    const int stride = gridDim.x * blockDim.x;
    for (; i < N_EDGES; i += stride) atomicAdd(&cnt[rows[i]], 1);
}

// ---------------- A2a: per-chunk inclusive scan; incl[i] stored at offs[i+1] --------
__global__ void __launch_bounds__(1024) scan1_kernel(const int* __restrict__ cnt,
                                                     int* __restrict__ offs,
                                                     int* __restrict__ partials) {
    __shared__ int s[2][CHUNK];
    const int t = threadIdx.x, b = blockIdx.x;
    const int i = b * CHUNK + t;
    s[0][t] = (i < N_NODES) ? cnt[i] : 0;
    __syncthreads();
    int src = 0;
    for (int off = 1; off < CHUNK; off <<= 1) {
        s[1 - src][t] = s[src][t] + (t >= off ? s[src][t - off] : 0);
        __syncthreads();
        src ^= 1;
    }
    const int incl = s[src][t];
    if (i < N_NODES) offs[i + 1] = incl;
    if (t == CHUNK - 1) partials[b] = incl;
}

// ---------------- A2b: exclusive scan of 98 chunk totals ----------------
__global__ void scan2_kernel(int* __restrict__ partials) {
    if (threadIdx.x == 0) {
        int run = 0;
        for (int i = 0; i < NCHUNK; ++i) {
            int v = partials[i];
            partials[i] = run;
            run += v;
        }
    }
}

// ---------------- A2c: finalize exclusive offs[], row cursor, coarse cursor --------
__global__ void __launch_bounds__(1024) scan3_kernel(int* __restrict__ offs,
                                                     const int* __restrict__ partials,
                                                     int* __restrict__ cursor,
                                                     int* __restrict__ ccursor) {
    const int i = blockIdx.x * CHUNK + threadIdx.x;  // 0..100351
    if (i > N_NODES) return;
    int val;
    if (i == 0) val = 0;
    else        val = offs[i] + partials[(i - 1) / CHUNK];
    offs[i] = val;
    if (i < N_NODES) {
        cursor[i] = val;
        if ((i & 1023) == 0) ccursor[i >> 10] = val;  // coarse bucket base
    }
}

// ---------------- R1: coarse scatter into 98 buckets (block-aggregated) ------------
// pack: m.x = (row&1023)<<17 | col   (col < 2^17), m.y = val bits
__global__ void __launch_bounds__(256) coarse_scatter_kernel(
        const int* __restrict__ rows, const int* __restrict__ cols,
        const float* __restrict__ vals, int* __restrict__ ccursor,
        int2* __restrict__ cbuf) {
    __shared__ int hist[NCB];
    __shared__ int base[NCB];
    __shared__ int lcur[NCB];
    const int t = threadIdx.x;
    const int b0 = blockIdx.x * R1_BATCH;
    for (int i = t; i < NCB; i += 256) { hist[i] = 0; lcur[i] = 0; }
    __syncthreads();

    int  mb[R1_PER_T];
    int2 md[R1_PER_T];
    #pragma unroll
    for (int k = 0; k < R1_PER_T; ++k) {
        const int e = b0 + k * 256 + t;  // coalesced
        if (e < N_EDGES) {
            const int r = rows[e];
            mb[k] = r >> 10;
            md[k] = make_int2(((r & 1023) << 17) | cols[e], __float_as_int(vals[e]));
            atomicAdd(&hist[mb[k]], 1);
        } else {
            mb[k] = -1;
        }
    }
    __syncthreads();
    for (int i = t; i < NCB; i += 256) {
        const int c = hist[i];
        base[i] = c ? atomicAdd(&ccursor[i], c) : 0;
    }
    __syncthreads();
    #pragma unroll
    for (int k = 0; k < R1_PER_T; ++k) {
        if (mb[k] >= 0) {
            const int rank = atomicAdd(&lcur[mb[k]], 1);
            cbuf[base[mb[k]] + rank] = md[k];
        }
    }
}

// ---------------- R2: fine scatter within bucket (one block per bucket) ------------
// All writes land in one 128KB ebuf window + 4KB cursor window -> L2-resident.
__global__ void __launch_bounds__(1024) fine_scatter_kernel(
        const int2* __restrict__ cbuf, const int* __restrict__ offs,
        int* __restrict__ cursor, int2* __restrict__ ebuf) {
    const int b = blockIdx.x;
    const int rowbase = b << 10;
    const int rend = min(rowbase + 1024, N_NODES);
    const int start = offs[rowbase];
    const int end   = offs[rend];
    for (int i = start + (int)threadIdx.x; i < end; i += 1024) {
        const int2 m = cbuf[i];
        const int row = rowbase + (m.x >> 17);
        const int pos = atomicAdd(&cursor[row], 1);
        ebuf[pos] = make_int2(m.x & 0x1FFFF, m.y);
    }
}

// ---------------- B: CSR SpMM, one wave per row, register accumulate, fused ReLU ----
__global__ void __launch_bounds__(256) spmm_csr_relu_kernel(
        const float* __restrict__ x, const int2* __restrict__ ebuf,
        const int* __restrict__ offs, float* __restrict__ out) {
    const int lane = threadIdx.x & 63;
    const int wave = threadIdx.x >> 6;
    const int r = blockIdx.x * 4 + wave;
    if (r >= N_NODES) return;
    const int start = offs[r];
    const int n = offs[r + 1] - start;

    float acc = 0.0f;
    for (int base = 0; base < n; base += 64) {
        const int take = min(64, n - base);
        int2 m = make_int2(0, 0);
        if (base + lane < n) m = ebuf[start + base + lane];  // coalesced meta load
        int j = 0;
        for (; j + 3 < take; j += 4) {
            const int   c0 = __shfl(m.x, j);
            const int   c1 = __shfl(m.x, j + 1);
            const int   c2 = __shfl(m.x, j + 2);
            const int   c3 = __shfl(m.x, j + 3);
            const float v0 = __int_as_float(__shfl(m.y, j));
            const float v1 = __int_as_float(__shfl(m.y, j + 1));
            const float v2 = __int_as_float(__shfl(m.y, j + 2));
            const float v3 = __int_as_float(__shfl(m.y, j + 3));
            const float x0 = x[(size_t)c0 * HIDDEN + lane];
            const float x1 = x[(size_t)c1 * HIDDEN + lane];
            const float x2 = x[(size_t)c2 * HIDDEN + lane];
            const float x3 = x[(size_t)c3 * HIDDEN + lane];
            acc = fmaf(v0, x0, acc);
            acc = fmaf(v1, x1, acc);
            acc = fmaf(v2, x2, acc);
            acc = fmaf(v3, x3, acc);
        }
        for (; j < take; ++j) {
            const int   c = __shfl(m.x, j);
            const float v = __int_as_float(__shfl(m.y, j));
            acc = fmaf(v, x[(size_t)c * HIDDEN + lane], acc);
        }
    }
    out[(size_t)r * HIDDEN + lane] = fmaxf(acc, 0.0f);
}

// ---------------- Tier-2 reorder (round-3 path, if ws can't fit cbuf) --------------
__global__ void reorder_kernel(const int* __restrict__ rows, const int* __restrict__ cols,
                               const float* __restrict__ vals, int* __restrict__ cursor,
                               int2* __restrict__ ebuf) {
    int i = blockIdx.x * blockDim.x + threadIdx.x;
    const int stride = gridDim.x * blockDim.x;
    for (; i < N_EDGES; i += stride) {
        const int pos = atomicAdd(&cursor[rows[i]], 1);
        ebuf[pos] = make_int2(cols[i], __float_as_int(vals[i]));
    }
}

// ---------------- Tier-3 fallback: global-atomic scatter ---------------------------
__global__ void spmm_scatter_kernel(const float* __restrict__ x,
                                    const int* __restrict__ rows,
                                    const int* __restrict__ cols,
                                    const float* __restrict__ vals,
                                    float* __restrict__ f) {
    const int lane = threadIdx.x & 63;
    const int wave = (blockIdx.x * blockDim.x + threadIdx.x) >> 6;
    const int nWaves = (gridDim.x * blockDim.x) >> 6;
    for (int e = wave; e < N_EDGES; e += nWaves)
        atomicAdd(&f[rows[e] * HIDDEN + lane], vals[e] * x[cols[e] * HIDDEN + lane]);
}
__global__ void relu_inplace_kernel(float4* __restrict__ f, int n4) {
    int i = blockIdx.x * blockDim.x + threadIdx.x;
    const int stride = gridDim.x * blockDim.x;
    for (; i < n4; i += stride) {
        float4 v = f[i];
        v.x = fmaxf(v.x, 0.0f); v.y = fmaxf(v.y, 0.0f);
        v.z = fmaxf(v.z, 0.0f); v.w = fmaxf(v.w, 0.0f);
        f[i] = v;
    }
}

extern "C" void kernel_launch(void* const* d_in, const int* in_sizes, int n_in,
                              void* d_out, int out_size, void* d_ws, size_t ws_size,
                              hipStream_t stream) {
    const float* x    = (const float*)d_in[1];
    const int*   rows = (const int*)d_in[2];
    const int*   cols = (const int*)d_in[3];
    const float* vals = (const float*)d_in[4];
    float* out = (float*)d_out;

    // ws layout: cnt[N] | offs[N+1] | partials[NCHUNK] | ccursor[NCB] | cbuf[E] | ebuf[E]
    const size_t cnt_off      = 0;
    const size_t offs_off     = cnt_off + (size_t)N_NODES * 4;
    const size_t partials_off = offs_off + (size_t)(N_NODES + 1) * 4;
    const size_t ccursor_off  = partials_off + (size_t)NCHUNK * 4;
    size_t cbuf_off = ccursor_off + (size_t)NCB * 4;
    cbuf_off = (cbuf_off + 15) & ~(size_t)15;
    const size_t ebuf_off = cbuf_off + (size_t)N_EDGES * 8;
    const size_t ws_full  = ebuf_off + (size_t)N_EDGES * 8;
    const size_t ws_tier2 = cbuf_off + (size_t)N_EDGES * 8;  // cbuf slot doubles as ebuf

    char* ws = (char*)d_ws;
    int*  cnt      = (int*)(ws + cnt_off);     // histogram, then per-row cursor
    int*  offs     = (int*)(ws + offs_off);
    int*  partials = (int*)(ws + partials_off);
    int*  ccursor  = (int*)(ws + ccursor_off);

    if (ws_size >= ws_full) {
        int2* cbuf = (int2*)(ws + cbuf_off);
        int2* ebuf = (int2*)(ws + ebuf_off);

        hipMemsetAsync(cnt, 0, (size_t)N_NODES * 4, stream);
        hist_kernel<<<2048, 256, 0, stream>>>(rows, cnt);
        scan1_kernel<<<NCHUNK, CHUNK, 0, stream>>>(cnt, offs, partials);
        scan2_kernel<<<1, 64, 0, stream>>>(partials);
        scan3_kernel<<<NCHUNK, CHUNK, 0, stream>>>(offs, partials, cnt, ccursor);
        coarse_scatter_kernel<<<(N_EDGES + R1_BATCH - 1) / R1_BATCH, 256, 0, stream>>>(
            rows, cols, vals, ccursor, cbuf);
        fine_scatter_kernel<<<NCB, 1024, 0, stream>>>(cbuf, offs, cnt, ebuf);
        spmm_csr_relu_kernel<<<N_NODES / 4, 256, 0, stream>>>(x, ebuf, offs, out);
    } else if (ws_size >= ws_tier2) {
        int2* ebuf = (int2*)(ws + cbuf_off);

        hipMemsetAsync(cnt, 0, (size_t)N_NODES * 4, stream);
        hist_kernel<<<2048, 256, 0, stream>>>(rows, cnt);
        scan1_kernel<<<NCHUNK, CHUNK, 0, stream>>>(cnt, offs, partials);
        scan2_kernel<<<1, 64, 0, stream>>>(partials);
        scan3_kernel<<<NCHUNK, CHUNK, 0, stream>>>(offs, partials, cnt, ccursor);
        reorder_kernel<<<2048, 256, 0, stream>>>(rows, cols, vals, cnt, ebuf);
        spmm_csr_relu_kernel<<<N_NODES / 4, 256, 0, stream>>>(x, ebuf, offs, out);
    } else {
        hipMemsetAsync(d_out, 0, (size_t)N_NODES * HIDDEN * sizeof(float), stream);
        spmm_scatter_kernel<<<2048, 256, 0, stream>>>(x, rows, cols, vals, out);
        relu_inplace_kernel<<<2048, 256, 0, stream>>>((float4*)d_out,
                                                      (N_NODES * HIDDEN) / 4);
    }
}

// Round 5
// 121.471 us; speedup vs baseline: 8.9729x; 1.7566x over previous
//
#include <hip/hip_runtime.h>

#define N_NODES 100000
#define N_EDGES 1600000
#define HIDDEN 64
#define RPB 512                                  // rows per coarse bucket
#define NCB ((N_NODES + RPB - 1) / RPB)          // 196 coarse buckets
#define NPART 256                                // coarse_hist blocks
#define R1_BATCH 4096
#define R1_PER_T (R1_BATCH / 256)                // 16 edges per thread

// ---------------- P1: coarse histogram, LDS-aggregated, no global atomics ----------
__global__ void __launch_bounds__(256) coarse_hist_kernel(const int* __restrict__ rows,
                                                          int* __restrict__ partials) {
    __shared__ int h[NCB];
    for (int i = threadIdx.x; i < NCB; i += 256) h[i] = 0;
    __syncthreads();
    int i = blockIdx.x * 256 + threadIdx.x;
    const int stride = NPART * 256;
    for (; i < N_EDGES; i += stride) atomicAdd(&h[rows[i] >> 9], 1);
    __syncthreads();
    for (int i = threadIdx.x; i < NCB; i += 256)
        partials[blockIdx.x * NCB + i] = h[i];
}

// ---------------- P2: reduce partials + exclusive scan of 196 buckets --------------
__global__ void __launch_bounds__(256) coarse_scan_kernel(const int* __restrict__ partials,
                                                          int* __restrict__ cbase,
                                                          int* __restrict__ ccursor,
                                                          int* __restrict__ offs) {
    __shared__ int s[2][256];
    const int t = threadIdx.x;
    int sum = 0;
    if (t < NCB)
        for (int b = 0; b < NPART; ++b) sum += partials[b * NCB + t];  // coalesced in t
    s[0][t] = sum;
    __syncthreads();
    int src = 0;
    for (int off = 1; off < 256; off <<= 1) {
        s[1 - src][t] = s[src][t] + (t >= off ? s[src][t - off] : 0);
        __syncthreads();
        src ^= 1;
    }
    if (t <= NCB) {
        const int v = t ? s[src][t - 1] : 0;   // exclusive
        cbase[t] = v;
        if (t < NCB) ccursor[t] = v;
    }
    if (t == 0) offs[N_NODES] = N_EDGES;
}

// ---------------- P3: coarse scatter into 196 buckets (block-aggregated) -----------
// pack: m.x = (row&511)<<17 | col   (col < 2^17), m.y = val bits
__global__ void __launch_bounds__(256) coarse_scatter_kernel(
        const int* __restrict__ rows, const int* __restrict__ cols,
        const float* __restrict__ vals, int* __restrict__ ccursor,
        int2* __restrict__ cbuf) {
    __shared__ int hist[NCB];
    __shared__ int base[NCB];
    __shared__ int lcur[NCB];
    const int t = threadIdx.x;
    const int b0 = blockIdx.x * R1_BATCH;
    for (int i = t; i < NCB; i += 256) { hist[i] = 0; lcur[i] = 0; }
    __syncthreads();

    int  mb[R1_PER_T];
    int2 md[R1_PER_T];
    #pragma unroll
    for (int k = 0; k < R1_PER_T; ++k) {
        const int e = b0 + k * 256 + t;  // coalesced
        if (e < N_EDGES) {
            const int r = rows[e];
            mb[k] = r >> 9;
            md[k] = make_int2(((r & 511) << 17) | cols[e], __float_as_int(vals[e]));
            atomicAdd(&hist[mb[k]], 1);
        } else {
            mb[k] = -1;
        }
    }
    __syncthreads();
    for (int i = t; i < NCB; i += 256) {
        const int c = hist[i];
        base[i] = c ? atomicAdd(&ccursor[i], c) : 0;
    }
    __syncthreads();
    #pragma unroll
    for (int k = 0; k < R1_PER_T; ++k) {
        if (mb[k] >= 0) {
            const int rank = atomicAdd(&lcur[mb[k]], 1);
            cbuf[base[mb[k]] + rank] = md[k];
        }
    }
}

// ---------------- P4: per-bucket LDS row-hist + scan + scatter; writes CSR offs ----
__global__ void __launch_bounds__(1024) fine_bucket_kernel(
        const int2* __restrict__ cbuf, const int* __restrict__ cbase,
        int* __restrict__ offs, int2* __restrict__ ebuf) {
    __shared__ int s[2][RPB];
    __shared__ int lcur[RPB];
    const int b = blockIdx.x;
    const int t = threadIdx.x;
    const int rowbase = b << 9;
    const int start = cbase[b], end = cbase[b + 1];

    if (t < RPB) s[0][t] = 0;
    __syncthreads();
    // pass 1: per-row counts in LDS
    for (int i = start + t; i < end; i += 1024)
        atomicAdd(&s[0][cbuf[i].x >> 17], 1);
    __syncthreads();
    // in-block inclusive scan over RPB counts (Hillis-Steele)
    int src = 0;
    for (int off = 1; off < RPB; off <<= 1) {
        if (t < RPB) s[1 - src][t] = s[src][t] + (t >= off ? s[src][t - off] : 0);
        __syncthreads();
        src ^= 1;
    }
    if (t < RPB) {
        const int excl = start + (t ? s[src][t - 1] : 0);
        const int row = rowbase + t;
        if (row < N_NODES) offs[row] = excl;   // global CSR offsets, no extra pass
        lcur[t] = excl;
    }
    __syncthreads();
    // pass 2: scatter within bucket via LDS cursors
    for (int i = start + t; i < end; i += 1024) {
        const int2 m = cbuf[i];
        const int pos = atomicAdd(&lcur[m.x >> 17], 1);
        ebuf[pos] = make_int2(m.x & 0x1FFFF, m.y);
    }
}

// ---------------- P5: CSR SpMM, one wave per row, register accumulate, fused ReLU --
__global__ void __launch_bounds__(256) spmm_csr_relu_kernel(
        const float* __restrict__ x, const int2* __restrict__ ebuf,
        const int* __restrict__ offs, float* __restrict__ out) {
    const int lane = threadIdx.x & 63;
    const int wave = threadIdx.x >> 6;
    const int r = blockIdx.x * 4 + wave;
    if (r >= N_NODES) return;
    const int start = offs[r];
    const int n = offs[r + 1] - start;

    float acc = 0.0f;
    for (int base = 0; base < n; base += 64) {
        const int take = min(64, n - base);
        int2 m = make_int2(0, 0);
        if (base + lane < n) m = ebuf[start + base + lane];  // coalesced meta load
        int j = 0;
        for (; j + 3 < take; j += 4) {
            const int   c0 = __shfl(m.x, j);
            const int   c1 = __shfl(m.x, j + 1);
            const int   c2 = __shfl(m.x, j + 2);
            const int   c3 = __shfl(m.x, j + 3);
            const float v0 = __int_as_float(__shfl(m.y, j));
            const float v1 = __int_as_float(__shfl(m.y, j + 1));
            const float v2 = __int_as_float(__shfl(m.y, j + 2));
            const float v3 = __int_as_float(__shfl(m.y, j + 3));
            const float x0 = x[(size_t)c0 * HIDDEN + lane];
            const float x1 = x[(size_t)c1 * HIDDEN + lane];
            const float x2 = x[(size_t)c2 * HIDDEN + lane];
            const float x3 = x[(size_t)c3 * HIDDEN + lane];
            acc = fmaf(v0, x0, acc);
            acc = fmaf(v1, x1, acc);
            acc = fmaf(v2, x2, acc);
            acc = fmaf(v3, x3, acc);
        }
        for (; j < take; ++j) {
            const int   c = __shfl(m.x, j);
            const float v = __int_as_float(__shfl(m.y, j));
            acc = fmaf(v, x[(size_t)c * HIDDEN + lane], acc);
        }
    }
    out[(size_t)r * HIDDEN + lane] = fmaxf(acc, 0.0f);
}

// ---------------- Fallback: global-atomic scatter (if ws too small) ----------------
__global__ void spmm_scatter_kernel(const float* __restrict__ x,
                                    const int* __restrict__ rows,
                                    const int* __restrict__ cols,
                                    const float* __restrict__ vals,
                                    float* __restrict__ f) {
    const int lane = threadIdx.x & 63;
    const int wave = (blockIdx.x * blockDim.x + threadIdx.x) >> 6;
    const int nWaves = (gridDim.x * blockDim.x) >> 6;
    for (int e = wave; e < N_EDGES; e += nWaves)
        atomicAdd(&f[rows[e] * HIDDEN + lane], vals[e] * x[cols[e] * HIDDEN + lane]);
}
__global__ void relu_inplace_kernel(float4* __restrict__ f, int n4) {
    int i = blockIdx.x * blockDim.x + threadIdx.x;
    const int stride = gridDim.x * blockDim.x;
    for (; i < n4; i += stride) {
        float4 v = f[i];
        v.x = fmaxf(v.x, 0.0f); v.y = fmaxf(v.y, 0.0f);
        v.z = fmaxf(v.z, 0.0f); v.w = fmaxf(v.w, 0.0f);
        f[i] = v;
    }
}

extern "C" void kernel_launch(void* const* d_in, const int* in_sizes, int n_in,
                              void* d_out, int out_size, void* d_ws, size_t ws_size,
                              hipStream_t stream) {
    const float* x    = (const float*)d_in[1];
    const int*   rows = (const int*)d_in[2];
    const int*   cols = (const int*)d_in[3];
    const float* vals = (const float*)d_in[4];
    float* out = (float*)d_out;

    // ws: partials[NPART*NCB] | cbase[NCB+1] | ccursor[NCB] | offs[N+1] | cbuf[E] | ebuf[E]
    const size_t partials_off = 0;
    const size_t cbase_off    = partials_off + (size_t)NPART * NCB * 4;
    const size_t ccursor_off  = cbase_off + (size_t)(NCB + 1) * 4;
    const size_t offs_off     = ccursor_off + (size_t)NCB * 4;
    size_t cbuf_off = offs_off + (size_t)(N_NODES + 1) * 4;
    cbuf_off = (cbuf_off + 15) & ~(size_t)15;
    const size_t ebuf_off = cbuf_off + (size_t)N_EDGES * 8;
    const size_t ws_full  = ebuf_off + (size_t)N_EDGES * 8;

    if (ws_size >= ws_full) {
        char* ws = (char*)d_ws;
        int*  partials = (int*)(ws + partials_off);
        int*  cbase    = (int*)(ws + cbase_off);
        int*  ccursor  = (int*)(ws + ccursor_off);
        int*  offs     = (int*)(ws + offs_off);
        int2* cbuf     = (int2*)(ws + cbuf_off);
        int2* ebuf     = (int2*)(ws + ebuf_off);

        coarse_hist_kernel<<<NPART, 256, 0, stream>>>(rows, partials);
        coarse_scan_kernel<<<1, 256, 0, stream>>>(partials, cbase, ccursor, offs);
        coarse_scatter_kernel<<<(N_EDGES + R1_BATCH - 1) / R1_BATCH, 256, 0, stream>>>(
            rows, cols, vals, ccursor, cbuf);
        fine_bucket_kernel<<<NCB, 1024, 0, stream>>>(cbuf, cbase, offs, ebuf);
        spmm_csr_relu_kernel<<<N_NODES / 4, 256, 0, stream>>>(x, ebuf, offs, out);
    } else {
        hipMemsetAsync(d_out, 0, (size_t)N_NODES * HIDDEN * sizeof(float), stream);
        spmm_scatter_kernel<<<2048, 256, 0, stream>>>(x, rows, cols, vals, out);
        relu_inplace_kernel<<<2048, 256, 0, stream>>>((float4*)d_out,
                                                      (N_NODES * HIDDEN) / 4);
    }
}

// Round 6
// 103.976 us; speedup vs baseline: 10.4827x; 1.1683x over previous
//
#include <hip/hip_runtime.h>

#define N_NODES 100000
#define N_EDGES 1600000
#define HIDDEN 64
#define RPB 512                                  // rows per coarse bucket
#define NCB ((N_NODES + RPB - 1) / RPB)          // 196 coarse buckets
#define CAP 8960                                 // padded bucket capacity (mean 8163 + 8.8 sigma)
#define NPART 256                                // tier-2 coarse_hist blocks
#define R1_BATCH 4096
#define R1_PER_T (R1_BATCH / 256)                // 16 edges per thread

// ================= PRIMARY PATH =================

// ---------------- P1: coarse scatter into padded buckets (block-aggregated) --------
// pack: m.x = (row&511)<<17 | col   (col < 2^17), m.y = val bits
// ccursor[] pre-zeroed; bucket b occupies cbuf[b*CAP .. b*CAP+count)
__global__ void __launch_bounds__(256) coarse_scatter_pad_kernel(
        const int* __restrict__ rows, const int* __restrict__ cols,
        const float* __restrict__ vals, int* __restrict__ ccursor,
        int2* __restrict__ cbuf) {
    __shared__ int hist[NCB];
    __shared__ int base[NCB];
    __shared__ int lcur[NCB];
    const int t = threadIdx.x;
    const int b0 = blockIdx.x * R1_BATCH;
    for (int i = t; i < NCB; i += 256) { hist[i] = 0; lcur[i] = 0; }
    __syncthreads();

    int  mb[R1_PER_T];
    int2 md[R1_PER_T];
    #pragma unroll
    for (int k = 0; k < R1_PER_T; ++k) {
        const int e = b0 + k * 256 + t;  // coalesced
        if (e < N_EDGES) {
            const int r = rows[e];
            mb[k] = r >> 9;
            md[k] = make_int2(((r & 511) << 17) | cols[e], __float_as_int(vals[e]));
            atomicAdd(&hist[mb[k]], 1);
        } else {
            mb[k] = -1;
        }
    }
    __syncthreads();
    for (int i = t; i < NCB; i += 256) {
        const int c = hist[i];
        base[i] = c ? (i * CAP + atomicAdd(&ccursor[i], c)) : 0;
    }
    __syncthreads();
    #pragma unroll
    for (int k = 0; k < R1_PER_T; ++k) {
        if (mb[k] >= 0) {
            const int rank = atomicAdd(&lcur[mb[k]], 1);
            cbuf[base[mb[k]] + rank] = md[k];
        }
    }
}

// ---------------- P2: exclusive scan of 196 bucket counts --------------------------
__global__ void __launch_bounds__(256) count_scan_kernel(const int* __restrict__ ccursor,
                                                         int* __restrict__ cbase,
                                                         int* __restrict__ offs) {
    __shared__ int s[2][256];
    const int t = threadIdx.x;
    s[0][t] = (t < NCB) ? ccursor[t] : 0;
    __syncthreads();
    int src = 0;
    for (int off = 1; off < 256; off <<= 1) {
        s[1 - src][t] = s[src][t] + (t >= off ? s[src][t - off] : 0);
        __syncthreads();
        src ^= 1;
    }
    if (t <= NCB) cbase[t] = t ? s[src][t - 1] : 0;
    if (t == 0) offs[N_NODES] = N_EDGES;
}

// ---------------- P3: per-bucket LDS row-hist + scan + scatter; writes CSR offs ----
__global__ void __launch_bounds__(1024) fine_bucket_pad_kernel(
        const int2* __restrict__ cbuf, const int* __restrict__ cbase,
        int* __restrict__ offs, int2* __restrict__ ebuf) {
    __shared__ int s[2][RPB];
    __shared__ int lcur[RPB];
    const int b = blockIdx.x;
    const int t = threadIdx.x;
    const int rowbase = b << 9;
    const int src0 = b * CAP;
    const int dst0 = cbase[b];
    const int cnt  = cbase[b + 1] - dst0;

    if (t < RPB) s[0][t] = 0;
    __syncthreads();
    for (int i = t; i < cnt; i += 1024)
        atomicAdd(&s[0][cbuf[src0 + i].x >> 17], 1);
    __syncthreads();
    int src = 0;
    for (int off = 1; off < RPB; off <<= 1) {
        if (t < RPB) s[1 - src][t] = s[src][t] + (t >= off ? s[src][t - off] : 0);
        __syncthreads();
        src ^= 1;
    }
    if (t < RPB) {
        const int excl = dst0 + (t ? s[src][t - 1] : 0);
        const int row = rowbase + t;
        if (row < N_NODES) offs[row] = excl;
        lcur[t] = excl;
    }
    __syncthreads();
    for (int i = t; i < cnt; i += 1024) {
        const int2 m = cbuf[src0 + i];
        const int pos = atomicAdd(&lcur[m.x >> 17], 1);
        ebuf[pos] = make_int2(m.x & 0x1FFFF, m.y);
    }
}

// ---------------- P4: CSR SpMM, float4 lane-groups, 4 edges/load, fused ReLU -------
// lane = g*16 + h: g = edge subgroup (0..3), h = float4 index within the 64-wide row.
__global__ void __launch_bounds__(256) spmm_csr_relu_f4_kernel(
        const float4* __restrict__ x4, const int2* __restrict__ ebuf,
        const int* __restrict__ offs, float4* __restrict__ out4) {
    const int lane = threadIdx.x & 63;
    const int g = lane >> 4;
    const int h = lane & 15;
    const int wave = threadIdx.x >> 6;
    const int r = blockIdx.x * 4 + wave;
    if (r >= N_NODES) return;
    const int start = offs[r];
    const int n = offs[r + 1] - start;

    float4 acc = make_float4(0.f, 0.f, 0.f, 0.f);
    for (int base = 0; base < n; base += 64) {
        const int take = min(64, n - base);
        int2 m = make_int2(0, 0);
        if (base + lane < n) m = ebuf[start + base + lane];  // coalesced meta load
        for (int j = 0; j < take; j += 8) {
            const int j0 = j + g;
            const int j1 = j + 4 + g;
            const bool p0 = j0 < take;
            const bool p1 = j1 < take;
            const int   c0r = __shfl(m.x, j0);
            const float v0r = __int_as_float(__shfl(m.y, j0));
            const int   c1r = __shfl(m.x, j1);
            const float v1r = __int_as_float(__shfl(m.y, j1));
            const int   c0 = p0 ? c0r : 0;
            const float v0 = p0 ? v0r : 0.0f;
            const int   c1 = p1 ? c1r : 0;
            const float v1 = p1 ? v1r : 0.0f;
            const float4 a = x4[(size_t)c0 * 16 + h];   // two loads in flight
            const float4 bq = x4[(size_t)c1 * 16 + h];
            acc.x = fmaf(v0, a.x, acc.x);  acc.y = fmaf(v0, a.y, acc.y);
            acc.z = fmaf(v0, a.z, acc.z);  acc.w = fmaf(v0, a.w, acc.w);
            acc.x = fmaf(v1, bq.x, acc.x); acc.y = fmaf(v1, bq.y, acc.y);
            acc.z = fmaf(v1, bq.z, acc.z); acc.w = fmaf(v1, bq.w, acc.w);
        }
    }
    // fold the 4 edge-subgroups (lanes differing in bits 4,5)
    acc.x += __shfl_xor(acc.x, 16); acc.y += __shfl_xor(acc.y, 16);
    acc.z += __shfl_xor(acc.z, 16); acc.w += __shfl_xor(acc.w, 16);
    acc.x += __shfl_xor(acc.x, 32); acc.y += __shfl_xor(acc.y, 32);
    acc.z += __shfl_xor(acc.z, 32); acc.w += __shfl_xor(acc.w, 32);
    if (lane < 16) {
        float4 o;
        o.x = fmaxf(acc.x, 0.f); o.y = fmaxf(acc.y, 0.f);
        o.z = fmaxf(acc.z, 0.f); o.w = fmaxf(acc.w, 0.f);
        out4[(size_t)r * 16 + h] = o;
    }
}

// ================= TIER-2 PATH (round-5 pipeline, smaller ws) =================

__global__ void __launch_bounds__(256) coarse_hist_kernel(const int* __restrict__ rows,
                                                          int* __restrict__ partials) {
    __shared__ int h[NCB];
    for (int i = threadIdx.x; i < NCB; i += 256) h[i] = 0;
    __syncthreads();
    int i = blockIdx.x * 256 + threadIdx.x;
    const int stride = NPART * 256;
    for (; i < N_EDGES; i += stride) atomicAdd(&h[rows[i] >> 9], 1);
    __syncthreads();
    for (int i = threadIdx.x; i < NCB; i += 256)
        partials[blockIdx.x * NCB + i] = h[i];
}

__global__ void __launch_bounds__(256) coarse_scan_kernel(const int* __restrict__ partials,
                                                          int* __restrict__ cbase,
                                                          int* __restrict__ ccursor,
                                                          int* __restrict__ offs) {
    __shared__ int s[2][256];
    const int t = threadIdx.x;
    int sum = 0;
    if (t < NCB)
        for (int b = 0; b < NPART; ++b) sum += partials[b * NCB + t];
    s[0][t] = sum;
    __syncthreads();
    int src = 0;
    for (int off = 1; off < 256; off <<= 1) {
        s[1 - src][t] = s[src][t] + (t >= off ? s[src][t - off] : 0);
        __syncthreads();
        src ^= 1;
    }
    if (t <= NCB) {
        const int v = t ? s[src][t - 1] : 0;
        cbase[t] = v;
        if (t < NCB) ccursor[t] = v;
    }
    if (t == 0) offs[N_NODES] = N_EDGES;
}

__global__ void __launch_bounds__(256) coarse_scatter_kernel(
        const int* __restrict__ rows, const int* __restrict__ cols,
        const float* __restrict__ vals, int* __restrict__ ccursor,
        int2* __restrict__ cbuf) {
    __shared__ int hist[NCB];
    __shared__ int base[NCB];
    __shared__ int lcur[NCB];
    const int t = threadIdx.x;
    const int b0 = blockIdx.x * R1_BATCH;
    for (int i = t; i < NCB; i += 256) { hist[i] = 0; lcur[i] = 0; }
    __syncthreads();
    int  mb[R1_PER_T];
    int2 md[R1_PER_T];
    #pragma unroll
    for (int k = 0; k < R1_PER_T; ++k) {
        const int e = b0 + k * 256 + t;
        if (e < N_EDGES) {
            const int r = rows[e];
            mb[k] = r >> 9;
            md[k] = make_int2(((r & 511) << 17) | cols[e], __float_as_int(vals[e]));
            atomicAdd(&hist[mb[k]], 1);
        } else mb[k] = -1;
    }
    __syncthreads();
    for (int i = t; i < NCB; i += 256) {
        const int c = hist[i];
        base[i] = c ? atomicAdd(&ccursor[i], c) : 0;
    }
    __syncthreads();
    #pragma unroll
    for (int k = 0; k < R1_PER_T; ++k) {
        if (mb[k] >= 0) {
            const int rank = atomicAdd(&lcur[mb[k]], 1);
            cbuf[base[mb[k]] + rank] = md[k];
        }
    }
}

__global__ void __launch_bounds__(1024) fine_bucket_kernel(
        const int2* __restrict__ cbuf, const int* __restrict__ cbase,
        int* __restrict__ offs, int2* __restrict__ ebuf) {
    __shared__ int s[2][RPB];
    __shared__ int lcur[RPB];
    const int b = blockIdx.x;
    const int t = threadIdx.x;
    const int rowbase = b << 9;
    const int start = cbase[b], end = cbase[b + 1];
    if (t < RPB) s[0][t] = 0;
    __syncthreads();
    for (int i = start + t; i < end; i += 1024)
        atomicAdd(&s[0][cbuf[i].x >> 17], 1);
    __syncthreads();
    int src = 0;
    for (int off = 1; off < RPB; off <<= 1) {
        if (t < RPB) s[1 - src][t] = s[src][t] + (t >= off ? s[src][t - off] : 0);
        __syncthreads();
        src ^= 1;
    }
    if (t < RPB) {
        const int excl = start + (t ? s[src][t - 1] : 0);
        const int row = rowbase + t;
        if (row < N_NODES) offs[row] = excl;
        lcur[t] = excl;
    }
    __syncthreads();
    for (int i = start + t; i < end; i += 1024) {
        const int2 m = cbuf[i];
        const int pos = atomicAdd(&lcur[m.x >> 17], 1);
        ebuf[pos] = make_int2(m.x & 0x1FFFF, m.y);
    }
}

// ================= TIER-3 fallback =================
__global__ void spmm_scatter_kernel(const float* __restrict__ x,
                                    const int* __restrict__ rows,
                                    const int* __restrict__ cols,
                                    const float* __restrict__ vals,
                                    float* __restrict__ f) {
    const int lane = threadIdx.x & 63;
    const int wave = (blockIdx.x * blockDim.x + threadIdx.x) >> 6;
    const int nWaves = (gridDim.x * blockDim.x) >> 6;
    for (int e = wave; e < N_EDGES; e += nWaves)
        atomicAdd(&f[rows[e] * HIDDEN + lane], vals[e] * x[cols[e] * HIDDEN + lane]);
}
__global__ void relu_inplace_kernel(float4* __restrict__ f, int n4) {
    int i = blockIdx.x * blockDim.x + threadIdx.x;
    const int stride = gridDim.x * blockDim.x;
    for (; i < n4; i += stride) {
        float4 v = f[i];
        v.x = fmaxf(v.x, 0.0f); v.y = fmaxf(v.y, 0.0f);
        v.z = fmaxf(v.z, 0.0f); v.w = fmaxf(v.w, 0.0f);
        f[i] = v;
    }
}

extern "C" void kernel_launch(void* const* d_in, const int* in_sizes, int n_in,
                              void* d_out, int out_size, void* d_ws, size_t ws_size,
                              hipStream_t stream) {
    const float* x    = (const float*)d_in[1];
    const int*   rows = (const int*)d_in[2];
    const int*   cols = (const int*)d_in[3];
    const float* vals = (const float*)d_in[4];
    float* out = (float*)d_out;
    char* ws = (char*)d_ws;

    // Primary ws: ccursor[NCB] | cbase[NCB+1] | offs[N+1] | cbuf[NCB*CAP] | ebuf[E]
    {
        const size_t ccursor_off = 0;
        const size_t cbase_off   = ccursor_off + (size_t)NCB * 4;
        const size_t offs_off    = cbase_off + (size_t)(NCB + 1) * 4;
        size_t cbuf_off = offs_off + (size_t)(N_NODES + 1) * 4;
        cbuf_off = (cbuf_off + 15) & ~(size_t)15;
        const size_t ebuf_off = cbuf_off + (size_t)NCB * CAP * 8;
        const size_t ws_need  = ebuf_off + (size_t)N_EDGES * 8;
        if (ws_size >= ws_need) {
            int*  ccursor = (int*)(ws + ccursor_off);
            int*  cbase   = (int*)(ws + cbase_off);
            int*  offs    = (int*)(ws + offs_off);
            int2* cbuf    = (int2*)(ws + cbuf_off);
            int2* ebuf    = (int2*)(ws + ebuf_off);

            hipMemsetAsync(ccursor, 0, (size_t)NCB * 4, stream);
            coarse_scatter_pad_kernel<<<(N_EDGES + R1_BATCH - 1) / R1_BATCH, 256, 0, stream>>>(
                rows, cols, vals, ccursor, cbuf);
            count_scan_kernel<<<1, 256, 0, stream>>>(ccursor, cbase, offs);
            fine_bucket_pad_kernel<<<NCB, 1024, 0, stream>>>(cbuf, cbase, offs, ebuf);
            spmm_csr_relu_f4_kernel<<<N_NODES / 4, 256, 0, stream>>>(
                (const float4*)x, ebuf, offs, (float4*)out);
            return;
        }
    }

    // Tier-2 ws: partials[NPART*NCB] | cbase[NCB+1] | ccursor[NCB] | offs[N+1] | cbuf[E] | ebuf[E]
    {
        const size_t partials_off = 0;
        const size_t cbase_off    = partials_off + (size_t)NPART * NCB * 4;
        const size_t ccursor_off  = cbase_off + (size_t)(NCB + 1) * 4;
        const size_t offs_off     = ccursor_off + (size_t)NCB * 4;
        size_t cbuf_off = offs_off + (size_t)(N_NODES + 1) * 4;
        cbuf_off = (cbuf_off + 15) & ~(size_t)15;
        const size_t ebuf_off = cbuf_off + (size_t)N_EDGES * 8;
        const size_t ws_need  = ebuf_off + (size_t)N_EDGES * 8;
        if (ws_size >= ws_need) {
            int*  partials = (int*)(ws + partials_off);
            int*  cbase    = (int*)(ws + cbase_off);
            int*  ccursor  = (int*)(ws + ccursor_off);
            int*  offs     = (int*)(ws + offs_off);
            int2* cbuf     = (int2*)(ws + cbuf_off);
            int2* ebuf     = (int2*)(ws + ebuf_off);

            coarse_hist_kernel<<<NPART, 256, 0, stream>>>(rows, partials);
            coarse_scan_kernel<<<1, 256, 0, stream>>>(partials, cbase, ccursor, offs);
            coarse_scatter_kernel<<<(N_EDGES + R1_BATCH - 1) / R1_BATCH, 256, 0, stream>>>(
                rows, cols, vals, ccursor, cbuf);
            fine_bucket_kernel<<<NCB, 1024, 0, stream>>>(cbuf, cbase, offs, ebuf);
            spmm_csr_relu_f4_kernel<<<N_NODES / 4, 256, 0, stream>>>(
                (const float4*)x, ebuf, offs, (float4*)out);
            return;
        }
    }

    // Tier-3: global-atomic scatter
    hipMemsetAsync(d_out, 0, (size_t)N_NODES * HIDDEN * sizeof(float), stream);
    spmm_scatter_kernel<<<2048, 256, 0, stream>>>(x, rows, cols, vals, out);
    relu_inplace_kernel<<<2048, 256, 0, stream>>>((float4*)d_out,
                                                  (N_NODES * HIDDEN) / 4);
}